// Round 1
// baseline (8810.674 us; speedup 1.0000x reference)
//
#include <hip/hip_runtime.h>
#include <cstdint>
#include <cstddef>

// Problem constants
#define BB 256
#define TT 20
#define NOBJ 36
#define OBJD 2048
#define ATTD 1024
#define DECD 1024
#define VOCAB 10000

// ---------------------------------------------------------------------------
// Sort: stable descending argsort of lengths (O(B^2), B=256, one block)
// ---------------------------------------------------------------------------
__global__ __launch_bounds__(256) void sort_kernel(
    const int* __restrict__ lens, int* __restrict__ sidx, int* __restrict__ slen,
    int* __restrict__ cnt, float* __restrict__ out_len, float* __restrict__ out_sind)
{
    __shared__ int L[BB];
    __shared__ int SL[BB];
    const int i = threadIdx.x;
    const int li = lens[i];
    L[i] = li;
    __syncthreads();
    int r = 0;
    for (int j = 0; j < BB; ++j) {
        const int lj = L[j];
        if (lj > li || (lj == li && j < i)) r++;
    }
    sidx[r] = i;
    slen[r] = li;
    SL[r] = li;
    out_sind[r] = (float)i;
    out_len[r]  = (float)li;
    __syncthreads();
    if (i < TT) {
        int cc = 0;
        for (int b = 0; b < BB; ++b) cc += (SL[b] > i);
        cnt[i] = cc;
    }
}

// ---------------------------------------------------------------------------
// Meta: sorted captions (as float output) + att1 row map
// ---------------------------------------------------------------------------
__global__ __launch_bounds__(256) void meta_kernel(
    const int* __restrict__ caps, const int* __restrict__ sidx,
    float* __restrict__ out_caps, int* __restrict__ rmap)
{
    const int idx = blockIdx.x * 256 + threadIdx.x;
    if (idx < BB * TT) {
        const int p = idx / TT, t = idx % TT;
        out_caps[idx] = (float)caps[sidx[p] * TT + t];
    }
    if (idx < BB * NOBJ) {
        rmap[idx] = sidx[idx / NOBJ] * NOBJ + (idx % NOBJ);
    }
}

// ---------------------------------------------------------------------------
// Embeddings: X[t*B+b, :] = (t==0 ? encoder_out[sidx[b]] : emb_table[cap[sidx[b], t-1]])
// ---------------------------------------------------------------------------
__global__ __launch_bounds__(256) void embed_kernel(
    const float* __restrict__ enc, const int* __restrict__ caps,
    const float* __restrict__ emb, const int* __restrict__ sidx,
    float* __restrict__ X)
{
    const int blk = blockIdx.x;          // t*B + b, grid = T*B
    const int t = blk >> 8;
    const int b = blk & 255;
    const int sb = sidx[b];
    const float* src = (t == 0) ? (enc + (size_t)sb * DECD)
                                : (emb + (size_t)caps[sb * TT + (t - 1)] * DECD);
    float4* dst = (float4*)(X + (size_t)blk * DECD);
    dst[threadIdx.x] = ((const float4*)src)[threadIdx.x];
}

// ---------------------------------------------------------------------------
// Wcat: stack [W_dec_att; W_fbeta; W_hh] (7168 x 1024) + bcat + bsum
// ---------------------------------------------------------------------------
__global__ __launch_bounds__(256) void wcat_kernel(
    const float* __restrict__ Wda, const float* __restrict__ bda,
    const float* __restrict__ Wfb, const float* __restrict__ bfb,
    const float* __restrict__ Whh, const float* __restrict__ bih,
    const float* __restrict__ bhh,
    float* __restrict__ Wcat, float* __restrict__ bcat, float* __restrict__ bsum)
{
    const int n = blockIdx.x;            // 0..7167
    const float* src;
    float bb;
    if (n < 1024)      { src = Wda + (size_t)n * 1024;          bb = bda[n]; }
    else if (n < 3072) { src = Wfb + (size_t)(n - 1024) * 1024; bb = bfb[n - 1024]; }
    else               { src = Whh + (size_t)(n - 3072) * 1024; bb = 0.f; }
    ((float4*)(Wcat + (size_t)n * 1024))[threadIdx.x] = ((const float4*)src)[threadIdx.x];
    if (threadIdx.x == 0) bcat[n] = bb;
    if (n < 4096 && threadIdx.x == 1) bsum[n] = bih[n] + bhh[n];
}

__global__ __launch_bounds__(256) void zero_hc(float* __restrict__ h, float* __restrict__ c)
{
    const int idx = blockIdx.x * 256 + threadIdx.x;   // grid 2048 -> 524288
    if (idx < BB * DECD) h[idx] = 0.f;
    else                 c[idx - BB * DECD] = 0.f;
}

// ---------------------------------------------------------------------------
// Generic f32 GEMM: C[m,n] = sum_k A[row(m), k] * W[n, k] + bias[n]
// 64x64 tile, 256 threads, 4x4 per thread, BK=16.
// row_map: optional A-row indirection. cntp: optional active-row count;
// rows >= *cntp are written as 0 (no bias).
// ---------------------------------------------------------------------------
__global__ __launch_bounds__(256) void gemm_bt(
    const float* __restrict__ A, int lda, const int* __restrict__ row_map,
    const float* __restrict__ W, int ldw,
    const float* __restrict__ bias,
    float* __restrict__ C, int ldc,
    int M, int N, int K,
    const int* __restrict__ cntp)
{
    __shared__ float As[16][68];
    __shared__ float Ws[16][68];
    const int tid = threadIdx.x;
    const int n0 = blockIdx.x * 64;
    const int m0 = blockIdx.y * 64;
    int act = M;
    if (cntp) act = *cntp;
    float acc[4][4] = {{0.f}};
    const int tm = (tid >> 4) << 2;
    const int tn = (tid & 15) << 2;
    if (m0 < act) {
        const int lr = tid >> 2;            // 0..63: tile row (for A) / tile col (for W)
        const int lk = (tid & 3) << 2;      // 0,4,8,12: k offset (float4)
        const int am = m0 + lr;
        const bool avalid = am < M;
        int asrc = 0;
        if (avalid) asrc = row_map ? row_map[am] : am;
        const float* arow = A + (size_t)asrc * lda + lk;
        const int wn = n0 + lr;
        const bool wvalid = wn < N;
        const float* wrow = W + (size_t)(wvalid ? wn : 0) * ldw + lk;
        for (int k0 = 0; k0 < K; k0 += 16) {
            float4 av = avalid ? *(const float4*)(arow + k0) : make_float4(0.f, 0.f, 0.f, 0.f);
            float4 wv = wvalid ? *(const float4*)(wrow + k0) : make_float4(0.f, 0.f, 0.f, 0.f);
            As[lk + 0][lr] = av.x; As[lk + 1][lr] = av.y; As[lk + 2][lr] = av.z; As[lk + 3][lr] = av.w;
            Ws[lk + 0][lr] = wv.x; Ws[lk + 1][lr] = wv.y; Ws[lk + 2][lr] = wv.z; Ws[lk + 3][lr] = wv.w;
            __syncthreads();
            #pragma unroll
            for (int k = 0; k < 16; ++k) {
                const float4 a4 = *(const float4*)&As[k][tm];
                const float4 b4 = *(const float4*)&Ws[k][tn];
                acc[0][0] = fmaf(a4.x, b4.x, acc[0][0]);
                acc[0][1] = fmaf(a4.x, b4.y, acc[0][1]);
                acc[0][2] = fmaf(a4.x, b4.z, acc[0][2]);
                acc[0][3] = fmaf(a4.x, b4.w, acc[0][3]);
                acc[1][0] = fmaf(a4.y, b4.x, acc[1][0]);
                acc[1][1] = fmaf(a4.y, b4.y, acc[1][1]);
                acc[1][2] = fmaf(a4.y, b4.z, acc[1][2]);
                acc[1][3] = fmaf(a4.y, b4.w, acc[1][3]);
                acc[2][0] = fmaf(a4.z, b4.x, acc[2][0]);
                acc[2][1] = fmaf(a4.z, b4.y, acc[2][1]);
                acc[2][2] = fmaf(a4.z, b4.z, acc[2][2]);
                acc[2][3] = fmaf(a4.z, b4.w, acc[2][3]);
                acc[3][0] = fmaf(a4.w, b4.x, acc[3][0]);
                acc[3][1] = fmaf(a4.w, b4.y, acc[3][1]);
                acc[3][2] = fmaf(a4.w, b4.z, acc[3][2]);
                acc[3][3] = fmaf(a4.w, b4.w, acc[3][3]);
            }
            __syncthreads();
        }
    }
    #pragma unroll
    for (int i = 0; i < 4; ++i) {
        const int m = m0 + tm + i;
        if (m >= M) break;
        float* crow = C + (size_t)m * ldc;
        const bool rowact = m < act;
        #pragma unroll
        for (int j = 0; j < 4; ++j) {
            const int n = n0 + tn + j;
            if (n < N) crow[n] = rowact ? (acc[i][j] + (bias ? bias[n] : 0.f)) : 0.f;
        }
    }
}

// ---------------------------------------------------------------------------
// Attention: e = relu(att1 + att2) @ w_full + b_full; softmax over 36;
// awe = (alpha @ objects) * sigmoid(gpre). One block per batch row.
// att2 = Hcat[:, 0:1024], gpre = Hcat[:, 1024:3072]. awe -> xcat[:, 1024:3072].
// ---------------------------------------------------------------------------
__global__ __launch_bounds__(256) void attn_kernel(
    const float* __restrict__ att1, const float* __restrict__ Hcat,
    const float* __restrict__ objs, const int* __restrict__ sidx,
    const float* __restrict__ wfa, const float* __restrict__ bfa,
    const int* __restrict__ slen, int t,
    float* __restrict__ out_alph, float* __restrict__ xcat)
{
    __shared__ float att2s[ATTD];
    __shared__ float red[4];
    __shared__ float es[NOBJ];
    __shared__ float alph[NOBJ + 4];
    const int b = blockIdx.x, tid = threadIdx.x;
    const float* hrow = Hcat + (size_t)b * 7168;
    #pragma unroll
    for (int j = 0; j < 4; ++j) att2s[tid + 256 * j] = hrow[tid + 256 * j];
    __syncthreads();
    for (int n = 0; n < NOBJ; ++n) {
        const float* a1 = att1 + ((size_t)(b * NOBJ + n)) * ATTD;
        float p = 0.f;
        #pragma unroll
        for (int j = 0; j < 4; ++j) {
            const int a = tid + 256 * j;
            float v = a1[a] + att2s[a];
            v = fmaxf(v, 0.f);
            p = fmaf(v, wfa[a], p);
        }
        #pragma unroll
        for (int off = 32; off > 0; off >>= 1) p += __shfl_down(p, off, 64);
        if ((tid & 63) == 0) red[tid >> 6] = p;
        __syncthreads();
        if (tid == 0) es[n] = red[0] + red[1] + red[2] + red[3] + bfa[0];
        __syncthreads();
    }
    if (tid == 0) {
        float m = es[0];
        for (int n = 1; n < NOBJ; ++n) m = fmaxf(m, es[n]);
        float s = 0.f;
        for (int n = 0; n < NOBJ; ++n) { const float e = expf(es[n] - m); alph[n] = e; s += e; }
        const float inv = 1.f / s;
        for (int n = 0; n < NOBJ; ++n) alph[n] *= inv;
    }
    __syncthreads();
    const bool active = t < slen[b];
    if (tid < NOBJ) out_alph[((size_t)b * TT + t) * NOBJ + tid] = active ? alph[tid] : 0.f;
    const float* ob = objs + (size_t)sidx[b] * (NOBJ * OBJD);
    float* aw = xcat + (size_t)b * 3072 + 1024;
    #pragma unroll
    for (int j = 0; j < 8; ++j) {
        const int o = tid + 256 * j;
        float accv = 0.f;
        #pragma unroll 4
        for (int n = 0; n < NOBJ; ++n) accv = fmaf(alph[n], ob[(size_t)n * OBJD + o], accv);
        const float g = 1.f / (1.f + expf(-hrow[1024 + o]));
        aw[o] = accv * g;
    }
}

// xcat[:, 0:1024] = X[t]
__global__ __launch_bounds__(256) void copyx_kernel(
    const float* __restrict__ X, float* __restrict__ xcat, int t)
{
    const int b = blockIdx.x;
    ((float4*)(xcat + (size_t)b * 3072))[threadIdx.x] =
        ((const float4*)(X + ((size_t)t * BB + b) * DECD))[threadIdx.x];
}

// ---------------------------------------------------------------------------
// LSTM elementwise: gates = G2 + Hcat[:, 3072:7168]; update h,c where active
// ---------------------------------------------------------------------------
__global__ __launch_bounds__(256) void lstm_kernel(
    const float* __restrict__ G2, const float* __restrict__ Hcat,
    float* __restrict__ h, float* __restrict__ c,
    const int* __restrict__ slen, int t)
{
    const int idx = blockIdx.x * 256 + threadIdx.x;   // 0..262143
    const int b = idx >> 10, d = idx & 1023;
    const float* g2 = G2 + (size_t)b * 4096;
    const float* hw = Hcat + (size_t)b * 7168 + 3072;
    const float ip = g2[d]        + hw[d];
    const float fp = g2[1024 + d] + hw[1024 + d];
    const float gp = g2[2048 + d] + hw[2048 + d];
    const float op = g2[3072 + d] + hw[3072 + d];
    const float si = 1.f / (1.f + expf(-ip));
    const float sf = 1.f / (1.f + expf(-fp));
    const float so = 1.f / (1.f + expf(-op));
    const float cn = sf * c[idx] + si * tanhf(gp);
    const float hn = so * tanhf(cn);
    if (t < slen[b]) { h[idx] = hn; c[idx] = cn; }
}

// ---------------------------------------------------------------------------
extern "C" void kernel_launch(void* const* d_in, const int* in_sizes, int n_in,
                              void* d_out, int out_size, void* d_ws, size_t ws_size,
                              hipStream_t stream)
{
    const float* enc  = (const float*)d_in[0];
    const float* objs = (const float*)d_in[1];
    const int*   caps = (const int*)d_in[2];
    const int*   clen = (const int*)d_in[3];
    const float* emb  = (const float*)d_in[4];
    const float* Wea  = (const float*)d_in[5];
    const float* bea  = (const float*)d_in[6];
    const float* Wda  = (const float*)d_in[7];
    const float* bda  = (const float*)d_in[8];
    const float* wfa  = (const float*)d_in[9];
    const float* bfa  = (const float*)d_in[10];
    const float* Wfb  = (const float*)d_in[11];
    const float* bfb  = (const float*)d_in[12];
    const float* Wih  = (const float*)d_in[13];
    const float* Whh  = (const float*)d_in[14];
    const float* bih  = (const float*)d_in[15];
    const float* bhh  = (const float*)d_in[16];
    const float* Wfc  = (const float*)d_in[17];
    const float* bfc  = (const float*)d_in[18];

    float* outP     = (float*)d_out;                       // (B,T,V)
    float* out_caps = outP + (size_t)BB * TT * VOCAB;      // (B,T)
    float* out_len  = out_caps + BB * TT;                  // (B,)
    float* out_alph = out_len + BB;                        // (B,T,36)
    float* out_sind = out_alph + (size_t)BB * TT * NOBJ;   // (B,)

    char* wp = (char*)d_ws;
    auto alloc = [&](size_t bytes) -> void* {
        void* r = (void*)wp;
        wp += (bytes + 255) & ~(size_t)255;
        return r;
    };
    int*   sidx = (int*)alloc(BB * 4);
    int*   slen = (int*)alloc(BB * 4);
    int*   cnt  = (int*)alloc(32 * 4);
    int*   rmap = (int*)alloc(BB * NOBJ * 4);
    float* att1 = (float*)alloc((size_t)BB * NOBJ * ATTD * 4);   // 37.75 MB
    float* Wcat = (float*)alloc((size_t)7168 * 1024 * 4);        // 29.4 MB
    float* bcat = (float*)alloc(7168 * 4);
    float* bsum = (float*)alloc(4096 * 4);
    float* X    = (float*)alloc((size_t)TT * BB * DECD * 4);     // 20 MB
    float* Hcat = (float*)alloc((size_t)BB * 7168 * 4);          // 7.3 MB
    float* xcat = (float*)alloc((size_t)BB * 3072 * 4);          // 3 MB
    float* G2   = (float*)alloc((size_t)BB * 4096 * 4);          // 4 MB
    float* h    = (float*)alloc((size_t)BB * DECD * 4);
    float* c    = (float*)alloc((size_t)BB * DECD * 4);
    (void)ws_size; (void)in_sizes; (void)n_in; (void)out_size;

    sort_kernel<<<1, 256, 0, stream>>>(clen, sidx, slen, cnt, out_len, out_sind);
    meta_kernel<<<36, 256, 0, stream>>>(caps, sidx, out_caps, rmap);
    embed_kernel<<<TT * BB, 256, 0, stream>>>(enc, caps, emb, sidx, X);
    wcat_kernel<<<7168, 256, 0, stream>>>(Wda, bda, Wfb, bfb, Whh, bih, bhh, Wcat, bcat, bsum);
    zero_hc<<<2048, 256, 0, stream>>>(h, c);

    // att1 = objects_sorted @ W_enc_att^T + b_enc_att  (M=9216, N=1024, K=2048)
    gemm_bt<<<dim3(16, 144), 256, 0, stream>>>(objs, OBJD, rmap, Wea, OBJD, bea,
                                               att1, ATTD, BB * NOBJ, ATTD, OBJD, nullptr);

    for (int t = 0; t < TT; ++t) {
        // Hcat = h @ [W_dec_att; W_fbeta; W_hh]^T + bcat  (M=256, N=7168, K=1024)
        gemm_bt<<<dim3(112, 4), 256, 0, stream>>>(h, DECD, nullptr, Wcat, 1024, bcat,
                                                  Hcat, 7168, BB, 7168, DECD, nullptr);
        // attention + gated awe -> xcat[:,1024:3072]
        attn_kernel<<<BB, 256, 0, stream>>>(att1, Hcat, objs, sidx, wfa, bfa, slen, t,
                                            out_alph, xcat);
        // xcat[:,0:1024] = x_t
        copyx_kernel<<<BB, 256, 0, stream>>>(X, xcat, t);
        // G2 = xcat @ W_ih^T + (b_ih + b_hh)  (M=256, N=4096, K=3072)
        gemm_bt<<<dim3(64, 4), 256, 0, stream>>>(xcat, 3072, nullptr, Wih, 3072, bsum,
                                                 G2, 4096, BB, 4096, 3072, nullptr);
        // LSTM update
        lstm_kernel<<<1024, 256, 0, stream>>>(G2, Hcat, h, c, slen, t);
        // preds = h_new @ W_fc^T + b_fc (masked rows -> 0)  (M=256, N=10000, K=1024)
        gemm_bt<<<dim3(157, 4), 256, 0, stream>>>(h, DECD, nullptr, Wfc, DECD, bfc,
                                                  outP + (size_t)t * VOCAB, TT * VOCAB,
                                                  BB, VOCAB, DECD, cnt + t);
    }
}

// Round 2
// 1993.800 us; speedup vs baseline: 4.4190x; 4.4190x over previous
//
#include <hip/hip_runtime.h>
#include <hip/hip_bf16.h>
#include <cstdint>
#include <cstddef>

#define BB 256
#define TT 20
#define NOBJ 36
#define OBJD 2048
#define ATTD 1024
#define DECD 1024
#define VOCAB 10000
#define NBIG  17168   // 7168 (Wda|Wfb|Whh) + 10000 (Wfc)
#define NBIGP 17216   // padded to multiple of 64
#define NSPLIT 7168

typedef unsigned short u16;
typedef __attribute__((ext_vector_type(8))) short short8v;
typedef __attribute__((ext_vector_type(4))) float float4v;

__device__ inline u16 f2bf(float f) {
    __hip_bfloat16 h = __float2bfloat16(f);
    return *reinterpret_cast<u16*>(&h);
}
__device__ inline float bu(u16 u) {
    union { unsigned int i; float f; } x;
    x.i = ((unsigned int)u) << 16;
    return x.f;
}
__device__ inline float sigf(float x) { return 1.f / (1.f + expf(-x)); }

// ---------------------------------------------------------------------------
// Sort: stable descending argsort of lengths (O(B^2), one block)
// ---------------------------------------------------------------------------
__global__ __launch_bounds__(256) void sort_kernel(
    const int* __restrict__ lens, int* __restrict__ sidx, int* __restrict__ slen,
    int* __restrict__ cnt, float* __restrict__ out_len, float* __restrict__ out_sind)
{
    __shared__ int L[BB];
    __shared__ int SL[BB];
    const int i = threadIdx.x;
    const int li = lens[i];
    L[i] = li;
    __syncthreads();
    int r = 0;
    for (int j = 0; j < BB; ++j) {
        const int lj = L[j];
        if (lj > li || (lj == li && j < i)) r++;
    }
    sidx[r] = i;
    slen[r] = li;
    SL[r] = li;
    out_sind[r] = (float)i;
    out_len[r]  = (float)li;
    __syncthreads();
    if (i < TT) {
        int cc = 0;
        for (int b = 0; b < BB; ++b) cc += (SL[b] > i);
        cnt[i] = cc;
    }
}

// sorted captions as float output
__global__ __launch_bounds__(256) void meta_kernel(
    const int* __restrict__ caps, const int* __restrict__ sidx,
    float* __restrict__ out_caps)
{
    const int idx = blockIdx.x * 256 + threadIdx.x;   // grid 20 -> 5120
    const int p = idx / TT, t = idx % TT;
    out_caps[idx] = (float)caps[sidx[p] * TT + t];
}

// gather objects in sorted order -> bf16 (9216 rows x 2048)
__global__ __launch_bounds__(256) void gather_objs(
    const float* __restrict__ objs, const int* __restrict__ sidx,
    u16* __restrict__ objsb)
{
    const int row = blockIdx.x;              // 0..9215
    const int b = row / NOBJ, n = row - b * NOBJ;
    const float* src = objs + ((size_t)sidx[b] * NOBJ + n) * OBJD;
    u16* dst = objsb + (size_t)row * OBJD;
    const int tid = threadIdx.x;
    #pragma unroll
    for (int j = 0; j < 2; ++j) {
        float4 v = ((const float4*)src)[tid + 256 * j];
        ushort4 s;
        s.x = f2bf(v.x); s.y = f2bf(v.y); s.z = f2bf(v.z); s.w = f2bf(v.w);
        ((ushort4*)dst)[tid + 256 * j] = s;
    }
}

// Wbig = [Wda;Wfb;Whh;Wfc;pad] (17216 x 1024) bf16 + bcat
__global__ __launch_bounds__(256) void convWbig(
    const float* __restrict__ Wda, const float* __restrict__ bda,
    const float* __restrict__ Wfb, const float* __restrict__ bfb,
    const float* __restrict__ Whh,
    const float* __restrict__ Wfc, const float* __restrict__ bfc,
    u16* __restrict__ Wb, float* __restrict__ bcat)
{
    const int n = blockIdx.x;                // 0..17215
    const int tid = threadIdx.x;
    const float* src = nullptr;
    float bb = 0.f;
    if (n < 1024)        { src = Wda + (size_t)n * 1024;            bb = bda[n]; }
    else if (n < 3072)   { src = Wfb + (size_t)(n - 1024) * 1024;   bb = bfb[n - 1024]; }
    else if (n < 7168)   { src = Whh + (size_t)(n - 3072) * 1024;   bb = 0.f; }
    else if (n < NBIG)   { src = Wfc + (size_t)(n - 7168) * 1024;   bb = bfc[n - 7168]; }
    u16* dst = Wb + (size_t)n * 1024;
    ushort4 s;
    if (src) {
        float4 v = ((const float4*)src)[tid];
        s.x = f2bf(v.x); s.y = f2bf(v.y); s.z = f2bf(v.z); s.w = f2bf(v.w);
    } else { s.x = s.y = s.z = s.w = 0; }
    ((ushort4*)dst)[tid] = s;
    if (tid == 0) bcat[n] = bb;
}

// Wih (4096 x 3072) bf16 + bsum = bih + bhh
__global__ __launch_bounds__(256) void convWih(
    const float* __restrict__ Wih, const float* __restrict__ bih,
    const float* __restrict__ bhh, u16* __restrict__ Wb, float* __restrict__ bsum)
{
    const int n = blockIdx.x;
    const int tid = threadIdx.x;
    const float* src = Wih + (size_t)n * 3072;
    u16* dst = Wb + (size_t)n * 3072;
    #pragma unroll
    for (int j = 0; j < 3; ++j) {
        float4 v = ((const float4*)src)[tid + 256 * j];
        ushort4 s;
        s.x = f2bf(v.x); s.y = f2bf(v.y); s.z = f2bf(v.z); s.w = f2bf(v.w);
        ((ushort4*)dst)[tid + 256 * j] = s;
    }
    if (tid == 0) bsum[n] = bih[n] + bhh[n];
}

// Wea (1024 x 2048) bf16
__global__ __launch_bounds__(256) void convWea(
    const float* __restrict__ Wea, u16* __restrict__ Wb)
{
    const int n = blockIdx.x;
    const int tid = threadIdx.x;
    const float* src = Wea + (size_t)n * OBJD;
    u16* dst = Wb + (size_t)n * OBJD;
    #pragma unroll
    for (int j = 0; j < 2; ++j) {
        float4 v = ((const float4*)src)[tid + 256 * j];
        ushort4 s;
        s.x = f2bf(v.x); s.y = f2bf(v.y); s.z = f2bf(v.z); s.w = f2bf(v.w);
        ((ushort4*)dst)[tid + 256 * j] = s;
    }
}

// X[t*B+b] bf16 = t==0 ? enc[sidx[b]] : emb[cap[sidx[b], t-1]]
__global__ __launch_bounds__(256) void embed_kernel(
    const float* __restrict__ enc, const int* __restrict__ caps,
    const float* __restrict__ emb, const int* __restrict__ sidx,
    u16* __restrict__ Xb)
{
    const int blk = blockIdx.x;     // grid T*B
    const int t = blk >> 8;
    const int b = blk & 255;
    const int sb = sidx[b];
    const float* src = (t == 0) ? (enc + (size_t)sb * DECD)
                                : (emb + (size_t)caps[sb * TT + (t - 1)] * DECD);
    const int tid = threadIdx.x;
    float4 v = ((const float4*)src)[tid];
    ushort4 s;
    s.x = f2bf(v.x); s.y = f2bf(v.y); s.z = f2bf(v.z); s.w = f2bf(v.w);
    ((ushort4*)(Xb + (size_t)blk * DECD))[tid] = s;
}

__global__ __launch_bounds__(256) void zero_hc(float* __restrict__ h, float* __restrict__ c)
{
    const int idx = blockIdx.x * 256 + threadIdx.x;
    if (idx < BB * DECD) h[idx] = 0.f;
    else                 c[idx - BB * DECD] = 0.f;
}

// Hcat(0) = broadcast bcat (h0 = 0)
__global__ __launch_bounds__(256) void hcat0_kernel(
    const float* __restrict__ bcat, float* __restrict__ Hcat)
{
    const int col4 = blockIdx.x * 256 + threadIdx.x;   // 0..1791 (7168/4)
    const int m = blockIdx.y;
    ((float4*)(Hcat + (size_t)m * 7168))[col4] = ((const float4*)bcat)[col4];
}

// ---------------------------------------------------------------------------
// bf16 MFMA GEMM: C[m,n] = sum_k A[m,k]*B[n,k] + bias[n]
// BM = 64*MF, BN = 64, BK = 32. 256 threads = 4 waves, wave owns 16*MF rows.
// LDS XOR swizzle: 16B slot(r,c) = 4r + (c ^ ((r>>1)&3))  (involution)
// Output: f32 C, or bf16 Cb if non-null. Split epilogue: n >= nsplit goes to
// C2[m, n-nsplit], zeroed for rows m >= *cntp.
// M must be a multiple of BM; B must have >= gridDim.x*64 rows (pad).
// ---------------------------------------------------------------------------
template<int MF>
__global__ __launch_bounds__(256) void gemm_mfma(
    const u16* __restrict__ A, int lda,
    const u16* __restrict__ B, int ldb,
    const float* __restrict__ bias,
    float* __restrict__ C, u16* __restrict__ Cb, int ldc,
    int Nreal, int K,
    int nsplit, float* __restrict__ C2, int ldc2, const int* __restrict__ cntp)
{
    constexpr int BM = 64 * MF;
    constexpr int BK = 32;
    __shared__ u16 As[BM * BK];
    __shared__ u16 Bs[64 * BK];
    const int tid = threadIdx.x;
    const int lane = tid & 63;
    const int w = tid >> 6;
    const int m0 = blockIdx.y * BM;
    const int n0 = blockIdx.x * 64;

    float4v acc[MF][4];
    #pragma unroll
    for (int i = 0; i < MF; ++i)
        #pragma unroll
        for (int j = 0; j < 4; ++j) acc[i][j] = (float4v){0.f, 0.f, 0.f, 0.f};

    // staging: A has BM*4 16B-slots (MF per thread), B has 256 (1 per thread)
    const int pa = tid * MF;
    const int ra = pa >> 2;
    const int fa = (ra >> 1) & 3;
    const int rb = tid >> 2;
    const int cbs = (tid & 3) ^ ((rb >> 1) & 3);
    const u16* Arow = A + (size_t)(m0 + ra) * lda;
    const u16* Brow = B + (size_t)(n0 + rb) * ldb;

    // fragment LDS slots (constant over k)
    const int cfrag = lane >> 4;
    int slotA[MF], slotB[4];
    #pragma unroll
    for (int mi = 0; mi < MF; ++mi) {
        const int r = w * (16 * MF) + mi * 16 + (lane & 15);
        slotA[mi] = 4 * r + (cfrag ^ ((r >> 1) & 3));
    }
    #pragma unroll
    for (int nj = 0; nj < 4; ++nj) {
        const int rn = nj * 16 + (lane & 15);
        slotB[nj] = 4 * rn + (cfrag ^ ((rn >> 1) & 3));
    }

    for (int k0 = 0; k0 < K; k0 += BK) {
        short8v ast[MF];
        #pragma unroll
        for (int s = 0; s < MF; ++s) {
            const int c = ((pa + s) & 3) ^ fa;
            ast[s] = *(const short8v*)(Arow + k0 + c * 8);
        }
        short8v bst = *(const short8v*)(Brow + k0 + cbs * 8);
        __syncthreads();
        #pragma unroll
        for (int s = 0; s < MF; ++s)
            *(short8v*)&As[(pa + s) * 8] = ast[s];
        *(short8v*)&Bs[tid * 8] = bst;
        __syncthreads();

        short8v av[MF], bv[4];
        #pragma unroll
        for (int mi = 0; mi < MF; ++mi) av[mi] = *(const short8v*)&As[slotA[mi] * 8];
        #pragma unroll
        for (int nj = 0; nj < 4; ++nj) bv[nj] = *(const short8v*)&Bs[slotB[nj] * 8];
        #pragma unroll
        for (int mi = 0; mi < MF; ++mi)
            #pragma unroll
            for (int nj = 0; nj < 4; ++nj)
                acc[mi][nj] = __builtin_amdgcn_mfma_f32_16x16x32_bf16(
                    av[mi], bv[nj], acc[mi][nj], 0, 0, 0);
    }

    const int act = cntp ? *cntp : (1 << 30);
    #pragma unroll
    for (int mi = 0; mi < MF; ++mi) {
        const int mbase = m0 + w * (16 * MF) + mi * 16 + ((lane >> 4) << 2);
        #pragma unroll
        for (int nj = 0; nj < 4; ++nj) {
            const int n = n0 + nj * 16 + (lane & 15);
            if (n >= Nreal) continue;
            const float bval = bias[n];
            #pragma unroll
            for (int r = 0; r < 4; ++r) {
                const int m = mbase + r;
                const float v = acc[mi][nj][r] + bval;
                if (n < nsplit) {
                    if (Cb) Cb[(size_t)m * ldc + n] = f2bf(v);
                    else    C [(size_t)m * ldc + n] = v;
                } else {
                    C2[(size_t)m * ldc2 + (n - nsplit)] = (m < act) ? v : 0.f;
                }
            }
        }
    }
}

// ---------------------------------------------------------------------------
// Attention: e = relu(att1 + att2) . w_full + b; softmax(36);
// awe = (alpha @ objects) * sigmoid(gate_pre); writes xcat bf16 (x_t | awe)
// One block per sorted batch row. att2 = Hcat[:,0:1024], gate = Hcat[:,1024:3072].
// ---------------------------------------------------------------------------
__global__ __launch_bounds__(256) void attn_kernel(
    const u16* __restrict__ att1b, const float* __restrict__ Hcat,
    const u16* __restrict__ objsb,
    const float* __restrict__ wfa, const float* __restrict__ bfa,
    const u16* __restrict__ Xb,
    const int* __restrict__ slen, int t,
    float* __restrict__ out_alph, u16* __restrict__ xcatb)
{
    __shared__ float wred[4][40];
    __shared__ float es[40];
    __shared__ float alph[40];
    const int b = blockIdx.x, tid = threadIdx.x;
    const int lane = tid & 63, w = tid >> 6;
    const float* hrow = Hcat + (size_t)b * 7168;
    const float4 h4 = ((const float4*)hrow)[tid];
    const float4 w4 = ((const float4*)wfa)[tid];
    const u16* a1base = att1b + (size_t)b * NOBJ * ATTD;

    float ep[NOBJ];
    #pragma unroll
    for (int n = 0; n < NOBJ; ++n) {
        ushort4 a4 = ((const ushort4*)(a1base + (size_t)n * ATTD))[tid];
        const float v0 = fmaxf(bu(a4.x) + h4.x, 0.f);
        const float v1 = fmaxf(bu(a4.y) + h4.y, 0.f);
        const float v2 = fmaxf(bu(a4.z) + h4.z, 0.f);
        const float v3 = fmaxf(bu(a4.w) + h4.w, 0.f);
        ep[n] = v0 * w4.x + v1 * w4.y + v2 * w4.z + v3 * w4.w;
    }
    #pragma unroll
    for (int n = 0; n < NOBJ; ++n) {
        float p = ep[n];
        #pragma unroll
        for (int off = 32; off > 0; off >>= 1) p += __shfl_down(p, off, 64);
        if (lane == 0) wred[w][n] = p;
    }
    __syncthreads();
    if (tid < NOBJ)
        es[tid] = wred[0][tid] + wred[1][tid] + wred[2][tid] + wred[3][tid] + bfa[0];
    __syncthreads();
    if (tid == 0) {
        float m = es[0];
        for (int n = 1; n < NOBJ; ++n) m = fmaxf(m, es[n]);
        float s = 0.f;
        for (int n = 0; n < NOBJ; ++n) { const float e = expf(es[n] - m); alph[n] = e; s += e; }
        const float inv = 1.f / s;
        for (int n = 0; n < NOBJ; ++n) alph[n] *= inv;
    }
    __syncthreads();
    const bool active = t < slen[b];
    if (tid < NOBJ)
        out_alph[((size_t)b * TT + t) * NOBJ + tid] = active ? alph[tid] : 0.f;

    // awe (8 contiguous obj-dims per thread)
    float acc[8] = {0.f, 0.f, 0.f, 0.f, 0.f, 0.f, 0.f, 0.f};
    const u16* ob = objsb + (size_t)b * NOBJ * OBJD + tid * 8;
    #pragma unroll 4
    for (int n = 0; n < NOBJ; ++n) {
        const short8v ov = *(const short8v*)(ob + (size_t)n * OBJD);
        const float al = alph[n];
        #pragma unroll
        for (int j = 0; j < 8; ++j) acc[j] = fmaf(al, bu((u16)ov[j]), acc[j]);
    }
    const float* gp = hrow + 1024 + tid * 8;
    const float4 g0 = *(const float4*)gp;
    const float4 g1 = *(const float4*)(gp + 4);
    float gt[8] = {sigf(g0.x), sigf(g0.y), sigf(g0.z), sigf(g0.w),
                   sigf(g1.x), sigf(g1.y), sigf(g1.z), sigf(g1.w)};
    short8v st;
    #pragma unroll
    for (int j = 0; j < 8; ++j) st[j] = (short)f2bf(acc[j] * gt[j]);
    *(short8v*)&xcatb[(size_t)b * 3072 + 1024 + tid * 8] = st;

    // x_t copy into xcat[:,0:1024]
    ((ushort4*)(xcatb + (size_t)b * 3072))[tid] =
        ((const ushort4*)(Xb + ((size_t)t * BB + b) * DECD))[tid];
}

// ---------------------------------------------------------------------------
// LSTM elementwise (float4), writes h/c (masked) and h_bf16 (always current h)
// ---------------------------------------------------------------------------
__global__ __launch_bounds__(256) void lstm_kernel(
    const float* __restrict__ G2, const float* __restrict__ Hcat,
    float* __restrict__ h, float* __restrict__ c, u16* __restrict__ hb,
    const int* __restrict__ slen, int t)
{
    const int idx = blockIdx.x * 256 + threadIdx.x;   // 65536 float4s
    const int b = idx >> 8, d4 = idx & 255;
    const float4* g2 = (const float4*)(G2 + (size_t)b * 4096);
    const float4* hw = (const float4*)(Hcat + (size_t)b * 7168 + 3072);
    const float4 vi = g2[d4],       wi = hw[d4];
    const float4 vf = g2[256 + d4], wf = hw[256 + d4];
    const float4 vg = g2[512 + d4], wg = hw[512 + d4];
    const float4 vo = g2[768 + d4], wo = hw[768 + d4];
    float4* hp = (float4*)(h + (size_t)b * 1024);
    float4* cp = (float4*)(c + (size_t)b * 1024);
    const float4 hold = hp[d4];
    const float4 cold = cp[d4];
    float4 cn, hn;
    {
        const float si = sigf(vi.x + wi.x), sf = sigf(vf.x + wf.x), so = sigf(vo.x + wo.x);
        cn.x = sf * cold.x + si * tanhf(vg.x + wg.x); hn.x = so * tanhf(cn.x);
    }
    {
        const float si = sigf(vi.y + wi.y), sf = sigf(vf.y + wf.y), so = sigf(vo.y + wo.y);
        cn.y = sf * cold.y + si * tanhf(vg.y + wg.y); hn.y = so * tanhf(cn.y);
    }
    {
        const float si = sigf(vi.z + wi.z), sf = sigf(vf.z + wf.z), so = sigf(vo.z + wo.z);
        cn.z = sf * cold.z + si * tanhf(vg.z + wg.z); hn.z = so * tanhf(cn.z);
    }
    {
        const float si = sigf(vi.w + wi.w), sf = sigf(vf.w + wf.w), so = sigf(vo.w + wo.w);
        cn.w = sf * cold.w + si * tanhf(vg.w + wg.w); hn.w = so * tanhf(cn.w);
    }
    const bool active = t < slen[b];
    const float4 hcur = active ? hn : hold;
    if (active) { hp[d4] = hn; cp[d4] = cn; }
    ushort4 s;
    s.x = f2bf(hcur.x); s.y = f2bf(hcur.y); s.z = f2bf(hcur.z); s.w = f2bf(hcur.w);
    ((ushort4*)(hb + (size_t)b * 1024))[d4] = s;
}

// ---------------------------------------------------------------------------
extern "C" void kernel_launch(void* const* d_in, const int* in_sizes, int n_in,
                              void* d_out, int out_size, void* d_ws, size_t ws_size,
                              hipStream_t stream)
{
    const float* enc  = (const float*)d_in[0];
    const float* objs = (const float*)d_in[1];
    const int*   caps = (const int*)d_in[2];
    const int*   clen = (const int*)d_in[3];
    const float* emb  = (const float*)d_in[4];
    const float* Wea  = (const float*)d_in[5];
    const float* bea  = (const float*)d_in[6];
    const float* Wda  = (const float*)d_in[7];
    const float* bda  = (const float*)d_in[8];
    const float* wfa  = (const float*)d_in[9];
    const float* bfa  = (const float*)d_in[10];
    const float* Wfb  = (const float*)d_in[11];
    const float* bfb  = (const float*)d_in[12];
    const float* Wih  = (const float*)d_in[13];
    const float* Whh  = (const float*)d_in[14];
    const float* bih  = (const float*)d_in[15];
    const float* bhh  = (const float*)d_in[16];
    const float* Wfc  = (const float*)d_in[17];
    const float* bfc  = (const float*)d_in[18];

    float* outP     = (float*)d_out;                       // (B,T,V)
    float* out_caps = outP + (size_t)BB * TT * VOCAB;      // (B,T)
    float* out_len  = out_caps + BB * TT;                  // (B,)
    float* out_alph = out_len + BB;                        // (B,T,36)
    float* out_sind = out_alph + (size_t)BB * TT * NOBJ;   // (B,)

    char* wp = (char*)d_ws;
    auto alloc = [&](size_t bytes) -> void* {
        void* r = (void*)wp;
        wp += (bytes + 255) & ~(size_t)255;
        return r;
    };
    int*   sidx  = (int*)alloc(BB * 4);
    int*   slen  = (int*)alloc(BB * 4);
    int*   cnt   = (int*)alloc(32 * 4);
    u16*   objsb = (u16*)alloc((size_t)BB * NOBJ * OBJD * 2);   // 37.75 MB
    u16*   Wbigb = (u16*)alloc((size_t)NBIGP * 1024 * 2);       // 35.3 MB
    float* bcat  = (float*)alloc(NBIGP * 4);
    u16*   Wihb  = (u16*)alloc((size_t)4096 * 3072 * 2);        // 25.2 MB
    float* bsum  = (float*)alloc(4096 * 4);
    u16*   Weab  = (u16*)alloc((size_t)1024 * OBJD * 2);        // 4.2 MB
    u16*   att1b = (u16*)alloc((size_t)BB * NOBJ * ATTD * 2);   // 18.9 MB
    u16*   Xb    = (u16*)alloc((size_t)TT * BB * DECD * 2);     // 10.5 MB
    float* Hcat  = (float*)alloc((size_t)BB * 7168 * 4);        // 7.3 MB
    u16*   xcatb = (u16*)alloc((size_t)BB * 3072 * 2);          // 1.5 MB
    float* G2    = (float*)alloc((size_t)BB * 4096 * 4);        // 4 MB
    float* h     = (float*)alloc((size_t)BB * DECD * 4);
    float* c     = (float*)alloc((size_t)BB * DECD * 4);
    u16*   hb    = (u16*)alloc((size_t)BB * DECD * 2);
    (void)ws_size; (void)in_sizes; (void)n_in; (void)out_size;

    sort_kernel<<<1, 256, 0, stream>>>(clen, sidx, slen, cnt, out_len, out_sind);
    meta_kernel<<<20, 256, 0, stream>>>(caps, sidx, out_caps);
    gather_objs<<<BB * NOBJ, 256, 0, stream>>>(objs, sidx, objsb);
    convWbig<<<NBIGP, 256, 0, stream>>>(Wda, bda, Wfb, bfb, Whh, Wfc, bfc, Wbigb, bcat);
    convWih<<<4096, 256, 0, stream>>>(Wih, bih, bhh, Wihb, bsum);
    convWea<<<1024, 256, 0, stream>>>(Wea, Weab);
    embed_kernel<<<TT * BB, 256, 0, stream>>>(enc, caps, emb, sidx, Xb);
    zero_hc<<<2048, 256, 0, stream>>>(h, c);
    hcat0_kernel<<<dim3(7, 256), 256, 0, stream>>>(bcat, Hcat);

    // att1 (bf16 out): M=9216, N=1024, K=2048
    gemm_mfma<2><<<dim3(16, 72), 256, 0, stream>>>(
        objsb, OBJD, Weab, OBJD, bea, nullptr, att1b, ATTD,
        ATTD, OBJD, 1 << 30, nullptr, 0, nullptr);

    for (int t = 0; t < TT; ++t) {
        attn_kernel<<<BB, 256, 0, stream>>>(att1b, Hcat, objsb, wfa, bfa, Xb,
                                            slen, t, out_alph, xcatb);
        // G2 = xcat @ Wih^T + bsum : M=256, N=4096, K=3072
        gemm_mfma<1><<<dim3(64, 4), 256, 0, stream>>>(
            xcatb, 3072, Wihb, 3072, bsum, G2, nullptr, 4096,
            4096, 3072, 1 << 30, nullptr, 0, nullptr);
        lstm_kernel<<<256, 256, 0, stream>>>(G2, Hcat, h, c, hb, slen, t);
        // fused: [Hcat(t+1) | preds(t)] = h @ Wbig^T + bcat : M=256, N=17168, K=1024
        gemm_mfma<2><<<dim3(NBIGP / 64, 2), 256, 0, stream>>>(
            hb, DECD, Wbigb, DECD, bcat, Hcat, nullptr, 7168,
            NBIG, DECD, NSPLIT, outP + (size_t)t * VOCAB, TT * VOCAB, cnt + t);
    }
}

// Round 3
// 1872.327 us; speedup vs baseline: 4.7057x; 1.0649x over previous
//
#include <hip/hip_runtime.h>
#include <hip/hip_bf16.h>
#include <cstdint>
#include <cstddef>

#define BB 256
#define TT 20
#define NOBJ 36
#define OBJD 2048
#define ATTD 1024
#define DECD 1024
#define VOCAB 10000
#define NBIG  17168   // 7168 (Wda|Wfb|Whh) + 10000 (Wfc)
#define NBIGP 17280   // padded to multiple of 128 (135 tiles)
#define NSPLIT 7168

typedef unsigned short u16;
typedef __attribute__((ext_vector_type(8))) short short8v;
typedef __attribute__((ext_vector_type(4))) float float4v;

__device__ inline u16 f2bf(float f) {
    __hip_bfloat16 h = __float2bfloat16(f);
    return *reinterpret_cast<u16*>(&h);
}
__device__ inline float bu(u16 u) {
    union { unsigned int i; float f; } x;
    x.i = ((unsigned int)u) << 16;
    return x.f;
}
__device__ inline float sigf(float x) { return 1.f / (1.f + expf(-x)); }

// async global->LDS, 16B per lane. LDS dest = wave-uniform base + lane*16.
__device__ inline void gload16(const u16* g, u16* l) {
    __builtin_amdgcn_global_load_lds(
        (const __attribute__((address_space(1))) unsigned int*)g,
        (__attribute__((address_space(3))) unsigned int*)l, 16, 0, 0);
}

// ---------------------------------------------------------------------------
// Sort: stable descending argsort of lengths (O(B^2), one block)
// ---------------------------------------------------------------------------
__global__ __launch_bounds__(256) void sort_kernel(
    const int* __restrict__ lens, int* __restrict__ sidx, int* __restrict__ slen,
    int* __restrict__ cnt, float* __restrict__ out_len, float* __restrict__ out_sind)
{
    __shared__ int L[BB];
    __shared__ int SL[BB];
    const int i = threadIdx.x;
    const int li = lens[i];
    L[i] = li;
    __syncthreads();
    int r = 0;
    for (int j = 0; j < BB; ++j) {
        const int lj = L[j];
        if (lj > li || (lj == li && j < i)) r++;
    }
    sidx[r] = i;
    slen[r] = li;
    SL[r] = li;
    out_sind[r] = (float)i;
    out_len[r]  = (float)li;
    __syncthreads();
    if (i < TT) {
        int cc = 0;
        for (int b = 0; b < BB; ++b) cc += (SL[b] > i);
        cnt[i] = cc;
    }
}

__global__ __launch_bounds__(256) void meta_kernel(
    const int* __restrict__ caps, const int* __restrict__ sidx,
    float* __restrict__ out_caps)
{
    const int idx = blockIdx.x * 256 + threadIdx.x;   // grid 20
    const int p = idx / TT, t = idx % TT;
    out_caps[idx] = (float)caps[sidx[p] * TT + t];
}

// gather objects in sorted order -> bf16 (9216 x 2048)
__global__ __launch_bounds__(256) void gather_objs(
    const float* __restrict__ objs, const int* __restrict__ sidx,
    u16* __restrict__ objsb)
{
    const int row = blockIdx.x;              // 0..9215
    const int b = row / NOBJ, n = row - b * NOBJ;
    const float* src = objs + ((size_t)sidx[b] * NOBJ + n) * OBJD;
    u16* dst = objsb + (size_t)row * OBJD;
    const int tid = threadIdx.x;
    #pragma unroll
    for (int j = 0; j < 2; ++j) {
        float4 v = ((const float4*)src)[tid + 256 * j];
        ushort4 s;
        s.x = f2bf(v.x); s.y = f2bf(v.y); s.z = f2bf(v.z); s.w = f2bf(v.w);
        ((ushort4*)dst)[tid + 256 * j] = s;
    }
}

// Wbig = [Wda;Wfb;Whh;Wfc;pad] (17280 x 1024) bf16 + bcat
__global__ __launch_bounds__(256) void convWbig(
    const float* __restrict__ Wda, const float* __restrict__ bda,
    const float* __restrict__ Wfb, const float* __restrict__ bfb,
    const float* __restrict__ Whh,
    const float* __restrict__ Wfc, const float* __restrict__ bfc,
    u16* __restrict__ Wb, float* __restrict__ bcat)
{
    const int n = blockIdx.x;                // 0..17279
    const int tid = threadIdx.x;
    const float* src = nullptr;
    float bb = 0.f;
    if (n < 1024)        { src = Wda + (size_t)n * 1024;            bb = bda[n]; }
    else if (n < 3072)   { src = Wfb + (size_t)(n - 1024) * 1024;   bb = bfb[n - 1024]; }
    else if (n < 7168)   { src = Whh + (size_t)(n - 3072) * 1024;   bb = 0.f; }
    else if (n < NBIG)   { src = Wfc + (size_t)(n - 7168) * 1024;   bb = bfc[n - 7168]; }
    u16* dst = Wb + (size_t)n * 1024;
    ushort4 s;
    if (src) {
        float4 v = ((const float4*)src)[tid];
        s.x = f2bf(v.x); s.y = f2bf(v.y); s.z = f2bf(v.z); s.w = f2bf(v.w);
    } else { s.x = s.y = s.z = s.w = 0; }
    ((ushort4*)dst)[tid] = s;
    if (tid == 0) bcat[n] = bb;
}

// Wih (4096 x 3072) bf16 + bsum = bih + bhh
__global__ __launch_bounds__(256) void convWih(
    const float* __restrict__ Wih, const float* __restrict__ bih,
    const float* __restrict__ bhh, u16* __restrict__ Wb, float* __restrict__ bsum)
{
    const int n = blockIdx.x;
    const int tid = threadIdx.x;
    const float* src = Wih + (size_t)n * 3072;
    u16* dst = Wb + (size_t)n * 3072;
    #pragma unroll
    for (int j = 0; j < 3; ++j) {
        float4 v = ((const float4*)src)[tid + 256 * j];
        ushort4 s;
        s.x = f2bf(v.x); s.y = f2bf(v.y); s.z = f2bf(v.z); s.w = f2bf(v.w);
        ((ushort4*)dst)[tid + 256 * j] = s;
    }
    if (tid == 0) bsum[n] = bih[n] + bhh[n];
}

// Wea (1024 x 2048) bf16
__global__ __launch_bounds__(256) void convWea(
    const float* __restrict__ Wea, u16* __restrict__ Wb)
{
    const int n = blockIdx.x;
    const int tid = threadIdx.x;
    const float* src = Wea + (size_t)n * OBJD;
    u16* dst = Wb + (size_t)n * OBJD;
    #pragma unroll
    for (int j = 0; j < 2; ++j) {
        float4 v = ((const float4*)src)[tid + 256 * j];
        ushort4 s;
        s.x = f2bf(v.x); s.y = f2bf(v.y); s.z = f2bf(v.z); s.w = f2bf(v.w);
        ((ushort4*)dst)[tid + 256 * j] = s;
    }
}

// X[t*B+b] bf16
__global__ __launch_bounds__(256) void embed_kernel(
    const float* __restrict__ enc, const int* __restrict__ caps,
    const float* __restrict__ emb, const int* __restrict__ sidx,
    u16* __restrict__ Xb)
{
    const int blk = blockIdx.x;     // grid T*B
    const int t = blk >> 8;
    const int b = blk & 255;
    const int sb = sidx[b];
    const float* src = (t == 0) ? (enc + (size_t)sb * DECD)
                                : (emb + (size_t)caps[sb * TT + (t - 1)] * DECD);
    const int tid = threadIdx.x;
    float4 v = ((const float4*)src)[tid];
    ushort4 s;
    s.x = f2bf(v.x); s.y = f2bf(v.y); s.z = f2bf(v.z); s.w = f2bf(v.w);
    ((ushort4*)(Xb + (size_t)blk * DECD))[tid] = s;
}

__global__ __launch_bounds__(256) void zero_hc(float* __restrict__ h, float* __restrict__ c)
{
    const int idx = blockIdx.x * 256 + threadIdx.x;
    if (idx < BB * DECD) h[idx] = 0.f;
    else                 c[idx - BB * DECD] = 0.f;
}

// Hcat(0) = broadcast bcat (h0 = 0)
__global__ __launch_bounds__(256) void hcat0_kernel(
    const float* __restrict__ bcat, float* __restrict__ Hcat)
{
    const int col4 = blockIdx.x * 256 + threadIdx.x;   // 0..1791
    const int m = blockIdx.y;
    ((float4*)(Hcat + (size_t)m * 7168))[col4] = ((const float4*)bcat)[col4];
}

// ---------------------------------------------------------------------------
// m97-structure bf16 MFMA GEMM. Tile 128x128, BK=32, 4 waves of 64x64 (4x4
// 16x16x32 frags). global_load_lds staging with source pre-swizzle
// (slot ^= (r>>1)&3, LDS linear), swizzled ds_read_b128 (2-way = free).
// C[m,n] = sum_k A[m, kz+k]*B[n, kz+k] + bias[n]; kz = blockIdx.z*kzlen.
// Output f32 Cf (+ z*zCstride) or bf16 Cb. Split: n >= nsplit -> C2, rows
// >= *cntp zeroed. Whole-block compute skip when m0 >= *cntp (rows masked
// downstream). M % 128 == 0 required; B must have gridDim.x*128 rows.
// ---------------------------------------------------------------------------
__global__ __launch_bounds__(256) void gemm128(
    const u16* __restrict__ A, int lda,
    const u16* __restrict__ B, int ldb,
    const float* __restrict__ bias,
    float* __restrict__ Cf, u16* __restrict__ Cb, int ldc,
    int Nreal, int kzlen, size_t zCstride,
    int nsplit, float* __restrict__ C2, int ldc2, const int* __restrict__ cntp)
{
    __shared__ u16 As[128 * 32];
    __shared__ u16 Bs[128 * 32];
    const int tid = threadIdx.x;
    const int lane = tid & 63;
    const int w = tid >> 6;
    const int wr = w >> 1, wc = w & 1;
    const int m0 = blockIdx.y * 128;
    const int n0 = blockIdx.x * 128;
    const int kbase = blockIdx.z * kzlen;
    A += kbase;
    B += kbase;
    if (Cf) Cf += (size_t)blockIdx.z * zCstride;

    const int act = cntp ? *cntp : (1 << 30);
    float4v acc[4][4];
    #pragma unroll
    for (int i = 0; i < 4; ++i)
        #pragma unroll
        for (int j = 0; j < 4; ++j) acc[i][j] = (float4v){0.f, 0.f, 0.f, 0.f};

    if (m0 < act) {
        // staging: 2 A-loads + 2 B-loads per wave, each 1KB (16 rows x 64B)
        const int r0 = (w * 2 + 0) * 16 + (lane >> 2);
        const int r1 = (w * 2 + 1) * 16 + (lane >> 2);
        const int s0 = (lane & 3) ^ ((r0 >> 1) & 3);
        const int s1 = (lane & 3) ^ ((r1 >> 1) & 3);
        const u16* gA0 = A + (size_t)(m0 + r0) * lda + s0 * 8;
        const u16* gA1 = A + (size_t)(m0 + r1) * lda + s1 * 8;
        const u16* gB0 = B + (size_t)(n0 + r0) * ldb + s0 * 8;
        const u16* gB1 = B + (size_t)(n0 + r1) * ldb + s1 * 8;
        u16* lA0 = &As[(w * 2 + 0) * 16 * 32];
        u16* lA1 = &As[(w * 2 + 1) * 16 * 32];
        u16* lB0 = &Bs[(w * 2 + 0) * 16 * 32];
        u16* lB1 = &Bs[(w * 2 + 1) * 16 * 32];

        // fragment LDS indices (u16 units), constant over k
        int ia[4], ib[4];
        #pragma unroll
        for (int mi = 0; mi < 4; ++mi) {
            const int r = wr * 64 + mi * 16 + (lane & 15);
            ia[mi] = r * 32 + (((lane >> 4) ^ ((r >> 1) & 3)) << 3);
        }
        #pragma unroll
        for (int nj = 0; nj < 4; ++nj) {
            const int r = wc * 64 + nj * 16 + (lane & 15);
            ib[nj] = r * 32 + (((lane >> 4) ^ ((r >> 1) & 3)) << 3);
        }

        const int nk = kzlen >> 5;
        for (int it = 0; it < nk; ++it) {
            gload16(gA0, lA0);
            gload16(gA1, lA1);
            gload16(gB0, lB0);
            gload16(gB1, lB1);
            gA0 += 32; gA1 += 32; gB0 += 32; gB1 += 32;
            __syncthreads();
            short8v av[4], bv[4];
            #pragma unroll
            for (int mi = 0; mi < 4; ++mi) av[mi] = *(const short8v*)&As[ia[mi]];
            #pragma unroll
            for (int nj = 0; nj < 4; ++nj) bv[nj] = *(const short8v*)&Bs[ib[nj]];
            #pragma unroll
            for (int mi = 0; mi < 4; ++mi)
                #pragma unroll
                for (int nj = 0; nj < 4; ++nj)
                    acc[mi][nj] = __builtin_amdgcn_mfma_f32_16x16x32_bf16(
                        av[mi], bv[nj], acc[mi][nj], 0, 0, 0);
            __syncthreads();
        }
    }

    #pragma unroll
    for (int mi = 0; mi < 4; ++mi) {
        const int mbase = m0 + wr * 64 + mi * 16 + ((lane >> 4) << 2);
        #pragma unroll
        for (int nj = 0; nj < 4; ++nj) {
            const int n = n0 + wc * 64 + nj * 16 + (lane & 15);
            if (n >= Nreal) continue;
            const float bval = bias ? bias[n] : 0.f;
            #pragma unroll
            for (int r = 0; r < 4; ++r) {
                const int m = mbase + r;
                const float v = acc[mi][nj][r] + bval;
                if (n < nsplit) {
                    if (Cb) Cb[(size_t)m * ldc + n] = f2bf(v);
                    else    Cf[(size_t)m * ldc + n] = v;
                } else {
                    C2[(size_t)m * ldc2 + (n - nsplit)] = (m < act) ? v : 0.f;
                }
            }
        }
    }
}

// ---------------------------------------------------------------------------
// Attention, z-split over obj dims: grid (B, 2). Both z compute e/softmax
// (redundant); z covers awe dims [z*1024, z*1024+1024). Inactive rows exit
// early (alphas zeroed by z=0). awe -> aweb bf16 (256 x 2048).
// ---------------------------------------------------------------------------
__global__ __launch_bounds__(256) void attn_kernel(
    const u16* __restrict__ att1b, const float* __restrict__ Hcat,
    const u16* __restrict__ objsb,
    const float* __restrict__ wfa, const float* __restrict__ bfa,
    const int* __restrict__ slen, int t,
    float* __restrict__ out_alph, u16* __restrict__ aweb)
{
    const int b = blockIdx.x, z = blockIdx.y, tid = threadIdx.x;
    const bool active = t < slen[b];
    if (!active) {
        if (z == 0 && tid < NOBJ)
            out_alph[((size_t)b * TT + t) * NOBJ + tid] = 0.f;
        return;
    }
    __shared__ float wred[4][40];
    __shared__ float es[40];
    __shared__ float alph[40];
    const int lane = tid & 63, w = tid >> 6;
    const float* hrow = Hcat + (size_t)b * 7168;
    const float4 h4 = ((const float4*)hrow)[tid];
    const float4 w4 = ((const float4*)wfa)[tid];
    const u16* a1base = att1b + (size_t)b * NOBJ * ATTD;

    float ep[NOBJ];
    #pragma unroll
    for (int n = 0; n < NOBJ; ++n) {
        ushort4 a4 = ((const ushort4*)(a1base + (size_t)n * ATTD))[tid];
        const float v0 = fmaxf(bu(a4.x) + h4.x, 0.f);
        const float v1 = fmaxf(bu(a4.y) + h4.y, 0.f);
        const float v2 = fmaxf(bu(a4.z) + h4.z, 0.f);
        const float v3 = fmaxf(bu(a4.w) + h4.w, 0.f);
        ep[n] = v0 * w4.x + v1 * w4.y + v2 * w4.z + v3 * w4.w;
    }
    #pragma unroll
    for (int n = 0; n < NOBJ; ++n) {
        float p = ep[n];
        #pragma unroll
        for (int off = 32; off > 0; off >>= 1) p += __shfl_down(p, off, 64);
        if (lane == 0) wred[w][n] = p;
    }
    __syncthreads();
    if (tid < NOBJ)
        es[tid] = wred[0][tid] + wred[1][tid] + wred[2][tid] + wred[3][tid] + bfa[0];
    __syncthreads();
    if (tid == 0) {
        float m = es[0];
        for (int n = 1; n < NOBJ; ++n) m = fmaxf(m, es[n]);
        float s = 0.f;
        for (int n = 0; n < NOBJ; ++n) { const float e = expf(es[n] - m); alph[n] = e; s += e; }
        const float inv = 1.f / s;
        for (int n = 0; n < NOBJ; ++n) alph[n] *= inv;
    }
    __syncthreads();
    if (z == 0 && tid < NOBJ)
        out_alph[((size_t)b * TT + t) * NOBJ + tid] = alph[tid];

    // awe: 4 contiguous dims per thread in this z-half
    float acc[4] = {0.f, 0.f, 0.f, 0.f};
    const u16* ob = objsb + (size_t)b * NOBJ * OBJD + z * 1024 + tid * 4;
    #pragma unroll 4
    for (int n = 0; n < NOBJ; ++n) {
        const ushort4 ov = *(const ushort4*)(ob + (size_t)n * OBJD);
        const float al = alph[n];
        acc[0] = fmaf(al, bu(ov.x), acc[0]);
        acc[1] = fmaf(al, bu(ov.y), acc[1]);
        acc[2] = fmaf(al, bu(ov.z), acc[2]);
        acc[3] = fmaf(al, bu(ov.w), acc[3]);
    }
    const float4 g0 = *(const float4*)(hrow + 1024 + z * 1024 + tid * 4);
    ushort4 st;
    st.x = f2bf(acc[0] * sigf(g0.x));
    st.y = f2bf(acc[1] * sigf(g0.y));
    st.z = f2bf(acc[2] * sigf(g0.z));
    st.w = f2bf(acc[3] * sigf(g0.w));
    *(ushort4*)&aweb[(size_t)b * 2048 + z * 1024 + tid * 4] = st;
}

// ---------------------------------------------------------------------------
// LSTM elementwise: gates = sum of 4 G2 partials + Gx[t] (bf16, has biases)
// + Hcat[:,3072:]; update h,c,hb. Inactive rows exit (hb persists).
// ---------------------------------------------------------------------------
__global__ __launch_bounds__(256) void lstm_kernel(
    const float* __restrict__ G2p, const u16* __restrict__ Gxb,
    const float* __restrict__ Hcat,
    float* __restrict__ h, float* __restrict__ c, u16* __restrict__ hb,
    const int* __restrict__ slen, int t)
{
    const int idx = blockIdx.x * 256 + threadIdx.x;   // 65536 float4 lanes
    const int b = idx >> 8, d4 = idx & 255;
    if (t >= slen[b]) return;
    const float4* pw = (const float4*)(Hcat + (size_t)b * 7168 + 3072);
    const u16* gx = Gxb + ((size_t)(t * BB + b)) * 4096;

    float4 g[4];   // i,f,g,o pre-activations
    #pragma unroll
    for (int q = 0; q < 4; ++q) {
        const ushort4 xv = ((const ushort4*)(gx + q * 1024))[d4];
        float4 s;
        s.x = bu(xv.x); s.y = bu(xv.y); s.z = bu(xv.z); s.w = bu(xv.w);
        const float4 hv = pw[q * 256 + d4];
        s.x += hv.x; s.y += hv.y; s.z += hv.z; s.w += hv.w;
        #pragma unroll
        for (int p = 0; p < 4; ++p) {
            const float4 pv = ((const float4*)G2p)[(size_t)p * (BB * 1024) + b * 1024 + q * 256 + d4];
            s.x += pv.x; s.y += pv.y; s.z += pv.z; s.w += pv.w;
        }
        g[q] = s;
    }
    float4* hp = (float4*)(h + (size_t)b * 1024);
    float4* cp = (float4*)(c + (size_t)b * 1024);
    const float4 cold = cp[d4];
    float4 cn, hn;
    {
        const float si = sigf(g[0].x), sf = sigf(g[1].x), so = sigf(g[3].x);
        cn.x = sf * cold.x + si * tanhf(g[2].x); hn.x = so * tanhf(cn.x);
    }
    {
        const float si = sigf(g[0].y), sf = sigf(g[1].y), so = sigf(g[3].y);
        cn.y = sf * cold.y + si * tanhf(g[2].y); hn.y = so * tanhf(cn.y);
    }
    {
        const float si = sigf(g[0].z), sf = sigf(g[1].z), so = sigf(g[3].z);
        cn.z = sf * cold.z + si * tanhf(g[2].z); hn.z = so * tanhf(cn.z);
    }
    {
        const float si = sigf(g[0].w), sf = sigf(g[1].w), so = sigf(g[3].w);
        cn.w = sf * cold.w + si * tanhf(g[2].w); hn.w = so * tanhf(cn.w);
    }
    hp[d4] = hn;
    cp[d4] = cn;
    ushort4 s;
    s.x = f2bf(hn.x); s.y = f2bf(hn.y); s.z = f2bf(hn.z); s.w = f2bf(hn.w);
    ((ushort4*)(hb + (size_t)b * 1024))[d4] = s;
}

// ---------------------------------------------------------------------------
extern "C" void kernel_launch(void* const* d_in, const int* in_sizes, int n_in,
                              void* d_out, int out_size, void* d_ws, size_t ws_size,
                              hipStream_t stream)
{
    const float* enc  = (const float*)d_in[0];
    const float* objs = (const float*)d_in[1];
    const int*   caps = (const int*)d_in[2];
    const int*   clen = (const int*)d_in[3];
    const float* emb  = (const float*)d_in[4];
    const float* Wea  = (const float*)d_in[5];
    const float* bea  = (const float*)d_in[6];
    const float* Wda  = (const float*)d_in[7];
    const float* bda  = (const float*)d_in[8];
    const float* wfa  = (const float*)d_in[9];
    const float* bfa  = (const float*)d_in[10];
    const float* Wfb  = (const float*)d_in[11];
    const float* bfb  = (const float*)d_in[12];
    const float* Wih  = (const float*)d_in[13];
    const float* Whh  = (const float*)d_in[14];
    const float* bih  = (const float*)d_in[15];
    const float* bhh  = (const float*)d_in[16];
    const float* Wfc  = (const float*)d_in[17];
    const float* bfc  = (const float*)d_in[18];

    float* outP     = (float*)d_out;                       // (B,T,V)
    float* out_caps = outP + (size_t)BB * TT * VOCAB;      // (B,T)
    float* out_len  = out_caps + BB * TT;                  // (B,)
    float* out_alph = out_len + BB;                        // (B,T,36)
    float* out_sind = out_alph + (size_t)BB * TT * NOBJ;   // (B,)

    char* wp = (char*)d_ws;
    auto alloc = [&](size_t bytes) -> void* {
        void* r = (void*)wp;
        wp += (bytes + 255) & ~(size_t)255;
        return r;
    };
    int*   sidx  = (int*)alloc(BB * 4);
    int*   slen  = (int*)alloc(BB * 4);
    int*   cnt   = (int*)alloc(32 * 4);
    u16*   objsb = (u16*)alloc((size_t)BB * NOBJ * OBJD * 2);   // 37.75 MB
    u16*   Wbigb = (u16*)alloc((size_t)NBIGP * 1024 * 2);       // 35.4 MB
    float* bcat  = (float*)alloc(NBIGP * 4);
    u16*   Wihb  = (u16*)alloc((size_t)4096 * 3072 * 2);        // 25.2 MB
    float* bsum  = (float*)alloc(4096 * 4);
    u16*   Weab  = (u16*)alloc((size_t)1024 * OBJD * 2);        // 4.2 MB
    u16*   att1b = (u16*)alloc((size_t)BB * NOBJ * ATTD * 2);   // 18.9 MB
    u16*   Xb    = (u16*)alloc((size_t)TT * BB * DECD * 2);     // 10.5 MB
    u16*   Gxb   = (u16*)alloc((size_t)TT * BB * 4096 * 2);     // 41.9 MB
    float* Hcat  = (float*)alloc((size_t)BB * 7168 * 4);        // 7.3 MB
    u16*   aweb  = (u16*)alloc((size_t)BB * 2048 * 2);          // 1 MB
    float* G2p   = (float*)alloc((size_t)4 * BB * 4096 * 4);    // 16.8 MB
    float* h     = (float*)alloc((size_t)BB * DECD * 4);
    float* c     = (float*)alloc((size_t)BB * DECD * 4);
    u16*   hb    = (u16*)alloc((size_t)BB * DECD * 2);
    (void)ws_size; (void)in_sizes; (void)n_in; (void)out_size;

    sort_kernel<<<1, 256, 0, stream>>>(clen, sidx, slen, cnt, out_len, out_sind);
    meta_kernel<<<20, 256, 0, stream>>>(caps, sidx, out_caps);
    gather_objs<<<BB * NOBJ, 256, 0, stream>>>(objs, sidx, objsb);
    convWbig<<<NBIGP, 256, 0, stream>>>(Wda, bda, Wfb, bfb, Whh, Wfc, bfc, Wbigb, bcat);
    convWih<<<4096, 256, 0, stream>>>(Wih, bih, bhh, Wihb, bsum);
    convWea<<<1024, 256, 0, stream>>>(Wea, Weab);
    embed_kernel<<<TT * BB, 256, 0, stream>>>(enc, caps, emb, sidx, Xb);
    zero_hc<<<2048, 256, 0, stream>>>(h, c);
    hcat0_kernel<<<dim3(7, 256), 256, 0, stream>>>(bcat, Hcat);

    // att1 (bf16): M=9216, N=1024, K=2048
    gemm128<<<dim3(8, 72, 1), 256, 0, stream>>>(
        objsb, OBJD, Weab, OBJD, bea, nullptr, att1b, ATTD,
        ATTD, OBJD, 0, 1 << 30, nullptr, 0, nullptr);

    // Gx = X @ Wih[:, :1024]^T + (bih+bhh) (bf16): M=5120, N=4096, K=1024
    gemm128<<<dim3(32, 40, 1), 256, 0, stream>>>(
        Xb, DECD, Wihb, 3072, bsum, nullptr, Gxb, 4096,
        4096, DECD, 0, 1 << 30, nullptr, 0, nullptr);

    for (int t = 0; t < TT; ++t) {
        attn_kernel<<<dim3(BB, 2), 256, 0, stream>>>(
            att1b, Hcat, objsb, wfa, bfa, slen, t, out_alph, aweb);
        // G2 partials = awe @ Wih[:,1024:3072]^T : M=256, N=4096, K=2048 (kz=4)
        gemm128<<<dim3(32, 2, 4), 256, 0, stream>>>(
            aweb, 2048, Wihb + 1024, 3072, nullptr, G2p, nullptr, 4096,
            4096, 512, (size_t)BB * 4096, 1 << 30, nullptr, 0, cnt + t);
        lstm_kernel<<<256, 256, 0, stream>>>(G2p, Gxb, Hcat, h, c, hb, slen, t);
        // fused: [Hcat(t+1) | preds(t)] = h @ Wbig^T + bcat : M=256, N=17168, K=1024
        gemm128<<<dim3(NBIGP / 128, 2, 1), 256, 0, stream>>>(
            hb, DECD, Wbigb, DECD, bcat, Hcat, nullptr, 7168,
            NBIG, DECD, 0, NSPLIT, outP + (size_t)t * VOCAB, TT * VOCAB, cnt + t);
    }
}

// Round 4
// 1703.515 us; speedup vs baseline: 5.1721x; 1.0991x over previous
//
#include <hip/hip_runtime.h>
#include <hip/hip_bf16.h>
#include <cstdint>
#include <cstddef>

#define BB 256
#define TT 20
#define NOBJ 36
#define OBJD 2048
#define ATTD 1024
#define DECD 1024
#define VOCAB 10000
#define NBIG  17168   // 7168 (Wda|Wfb|Whh) + 10000 (Wfc)
#define NBIGP 17280   // padded to multiple of 128 (135 tiles)
#define NSPLIT 7168

typedef unsigned short u16;
typedef __attribute__((ext_vector_type(8))) short short8v;
typedef __attribute__((ext_vector_type(4))) float float4v;

__device__ inline u16 f2bf(float f) {
    __hip_bfloat16 h = __float2bfloat16(f);
    return *reinterpret_cast<u16*>(&h);
}
__device__ inline float bu(u16 u) {
    union { unsigned int i; float f; } x;
    x.i = ((unsigned int)u) << 16;
    return x.f;
}
__device__ inline float sigf(float x) { return 1.f / (1.f + expf(-x)); }

// async global->LDS, 16B per lane. LDS dest must be wave-uniform base.
__device__ inline void gload16(const u16* g, u16* l) {
    __builtin_amdgcn_global_load_lds(
        (const __attribute__((address_space(1))) unsigned int*)g,
        (__attribute__((address_space(3))) unsigned int*)l, 16, 0, 0);
}

// ---------------------------------------------------------------------------
// Sort: stable descending argsort of lengths (O(B^2), one block)
// ---------------------------------------------------------------------------
__global__ __launch_bounds__(256) void sort_kernel(
    const int* __restrict__ lens, int* __restrict__ sidx, int* __restrict__ slen,
    int* __restrict__ cnt, float* __restrict__ out_len, float* __restrict__ out_sind)
{
    __shared__ int L[BB];
    __shared__ int SL[BB];
    const int i = threadIdx.x;
    const int li = lens[i];
    L[i] = li;
    __syncthreads();
    int r = 0;
    for (int j = 0; j < BB; ++j) {
        const int lj = L[j];
        if (lj > li || (lj == li && j < i)) r++;
    }
    sidx[r] = i;
    slen[r] = li;
    SL[r] = li;
    out_sind[r] = (float)i;
    out_len[r]  = (float)li;
    __syncthreads();
    if (i < TT) {
        int cc = 0;
        for (int b = 0; b < BB; ++b) cc += (SL[b] > i);
        cnt[i] = cc;
    }
}

__global__ __launch_bounds__(256) void meta_kernel(
    const int* __restrict__ caps, const int* __restrict__ sidx,
    float* __restrict__ out_caps)
{
    const int idx = blockIdx.x * 256 + threadIdx.x;   // grid 20
    const int p = idx / TT, t = idx % TT;
    out_caps[idx] = (float)caps[sidx[p] * TT + t];
}

// gather objects in sorted order -> bf16 (9216 x 2048)
__global__ __launch_bounds__(256) void gather_objs(
    const float* __restrict__ objs, const int* __restrict__ sidx,
    u16* __restrict__ objsb)
{
    const int row = blockIdx.x;              // 0..9215
    const int b = row / NOBJ, n = row - b * NOBJ;
    const float* src = objs + ((size_t)sidx[b] * NOBJ + n) * OBJD;
    u16* dst = objsb + (size_t)row * OBJD;
    const int tid = threadIdx.x;
    #pragma unroll
    for (int j = 0; j < 2; ++j) {
        float4 v = ((const float4*)src)[tid + 256 * j];
        ushort4 s;
        s.x = f2bf(v.x); s.y = f2bf(v.y); s.z = f2bf(v.z); s.w = f2bf(v.w);
        ((ushort4*)dst)[tid + 256 * j] = s;
    }
}

// Wbig = [Wda;Wfb;Whh;Wfc;pad] (17280 x 1024) bf16 + bcat
__global__ __launch_bounds__(256) void convWbig(
    const float* __restrict__ Wda, const float* __restrict__ bda,
    const float* __restrict__ Wfb, const float* __restrict__ bfb,
    const float* __restrict__ Whh,
    const float* __restrict__ Wfc, const float* __restrict__ bfc,
    u16* __restrict__ Wb, float* __restrict__ bcat)
{
    const int n = blockIdx.x;                // 0..17279
    const int tid = threadIdx.x;
    const float* src = nullptr;
    float bb = 0.f;
    if (n < 1024)        { src = Wda + (size_t)n * 1024;            bb = bda[n]; }
    else if (n < 3072)   { src = Wfb + (size_t)(n - 1024) * 1024;   bb = bfb[n - 1024]; }
    else if (n < 7168)   { src = Whh + (size_t)(n - 3072) * 1024;   bb = 0.f; }
    else if (n < NBIG)   { src = Wfc + (size_t)(n - 7168) * 1024;   bb = bfc[n - 7168]; }
    u16* dst = Wb + (size_t)n * 1024;
    ushort4 s;
    if (src) {
        float4 v = ((const float4*)src)[tid];
        s.x = f2bf(v.x); s.y = f2bf(v.y); s.z = f2bf(v.z); s.w = f2bf(v.w);
    } else { s.x = s.y = s.z = s.w = 0; }
    ((ushort4*)dst)[tid] = s;
    if (tid == 0) bcat[n] = bb;
}

// Wih (4096 x 3072) bf16 + bsum = bih + bhh
__global__ __launch_bounds__(256) void convWih(
    const float* __restrict__ Wih, const float* __restrict__ bih,
    const float* __restrict__ bhh, u16* __restrict__ Wb, float* __restrict__ bsum)
{
    const int n = blockIdx.x;
    const int tid = threadIdx.x;
    const float* src = Wih + (size_t)n * 3072;
    u16* dst = Wb + (size_t)n * 3072;
    #pragma unroll
    for (int j = 0; j < 3; ++j) {
        float4 v = ((const float4*)src)[tid + 256 * j];
        ushort4 s;
        s.x = f2bf(v.x); s.y = f2bf(v.y); s.z = f2bf(v.z); s.w = f2bf(v.w);
        ((ushort4*)dst)[tid + 256 * j] = s;
    }
    if (tid == 0) bsum[n] = bih[n] + bhh[n];
}

// Wea (1024 x 2048) bf16
__global__ __launch_bounds__(256) void convWea(
    const float* __restrict__ Wea, u16* __restrict__ Wb)
{
    const int n = blockIdx.x;
    const int tid = threadIdx.x;
    const float* src = Wea + (size_t)n * OBJD;
    u16* dst = Wb + (size_t)n * OBJD;
    #pragma unroll
    for (int j = 0; j < 2; ++j) {
        float4 v = ((const float4*)src)[tid + 256 * j];
        ushort4 s;
        s.x = f2bf(v.x); s.y = f2bf(v.y); s.z = f2bf(v.z); s.w = f2bf(v.w);
        ((ushort4*)dst)[tid + 256 * j] = s;
    }
}

// X[t*B+b] bf16
__global__ __launch_bounds__(256) void embed_kernel(
    const float* __restrict__ enc, const int* __restrict__ caps,
    const float* __restrict__ emb, const int* __restrict__ sidx,
    u16* __restrict__ Xb)
{
    const int blk = blockIdx.x;     // grid T*B
    const int t = blk >> 8;
    const int b = blk & 255;
    const int sb = sidx[b];
    const float* src = (t == 0) ? (enc + (size_t)sb * DECD)
                                : (emb + (size_t)caps[sb * TT + (t - 1)] * DECD);
    const int tid = threadIdx.x;
    float4 v = ((const float4*)src)[tid];
    ushort4 s;
    s.x = f2bf(v.x); s.y = f2bf(v.y); s.z = f2bf(v.z); s.w = f2bf(v.w);
    ((ushort4*)(Xb + (size_t)blk * DECD))[tid] = s;
}

__global__ __launch_bounds__(256) void zero_hc(float* __restrict__ h, float* __restrict__ c)
{
    const int idx = blockIdx.x * 256 + threadIdx.x;
    if (idx < BB * DECD) h[idx] = 0.f;
    else                 c[idx - BB * DECD] = 0.f;
}

// Hcat(0) = broadcast bcat (h0 = 0)
__global__ __launch_bounds__(256) void hcat0_kernel(
    const float* __restrict__ bcat, float* __restrict__ Hcat)
{
    const int col4 = blockIdx.x * 256 + threadIdx.x;   // 0..1791
    const int m = blockIdx.y;
    ((float4*)(Hcat + (size_t)m * 7168))[col4] = ((const float4*)bcat)[col4];
}

// ---------------------------------------------------------------------------
// 3-deep pipelined bf16 MFMA GEMM. Tile 128x128, BK=32, 4 waves of 64x64.
// global_load_lds with source pre-swizzle (LDS linear), swizzled ds_read_b128.
// Pipeline: 3 LDS buffer pairs; tiles staged 3 ahead; counted s_waitcnt
// vmcnt(8)/4/0 + raw s_barrier (never vmcnt(0) mid-loop).
// pairM: blockIdx.x encodes (n,m) as (bid>>1, bid&1) so both m-tiles of one
// B-panel are dispatch-adjacent (same XCD L2).
// C[m,n] = sum_k A[m, kz+k]*B[n, kz+k] + bias[n]; kz = blockIdx.z*kzlen.
// n >= nsplit -> C2 with rows >= *cntp zeroed; block-skip when m0 >= *cntp.
// ---------------------------------------------------------------------------
__global__ __launch_bounds__(256) void gemm128(
    const u16* __restrict__ A, int lda,
    const u16* __restrict__ B, int ldb,
    const float* __restrict__ bias,
    float* __restrict__ Cf, u16* __restrict__ Cb, int ldc,
    int Nreal, int kzlen, size_t zCstride, int pairM,
    int nsplit, float* __restrict__ C2, int ldc2, const int* __restrict__ cntp)
{
    __shared__ u16 As[3][128 * 32];
    __shared__ u16 Bs[3][128 * 32];
    const int tid = threadIdx.x;
    const int lane = tid & 63;
    const int w = tid >> 6;
    const int wr = w >> 1, wc = w & 1;
    int nIdx, mIdx;
    if (pairM) { nIdx = blockIdx.x >> 1; mIdx = blockIdx.x & 1; }
    else       { nIdx = blockIdx.x;      mIdx = blockIdx.y; }
    const int m0 = mIdx * 128;
    const int n0 = nIdx * 128;
    const int kbase = blockIdx.z * kzlen;
    A += kbase;
    B += kbase;
    if (Cf) Cf += (size_t)blockIdx.z * zCstride;

    const int act = cntp ? *cntp : (1 << 30);
    float4v acc[4][4];
    #pragma unroll
    for (int i = 0; i < 4; ++i)
        #pragma unroll
        for (int j = 0; j < 4; ++j) acc[i][j] = (float4v){0.f, 0.f, 0.f, 0.f};

    if (m0 < act) {
        // staging geometry: per wave 2 A-chunks + 2 B-chunks of 16 rows x 64B
        const int r0 = (w * 2 + 0) * 16 + (lane >> 2);
        const int r1 = (w * 2 + 1) * 16 + (lane >> 2);
        const int s0 = (lane & 3) ^ ((r0 >> 1) & 3);
        const int s1 = (lane & 3) ^ ((r1 >> 1) & 3);
        const u16* gA0 = A + (size_t)(m0 + r0) * lda + s0 * 8;
        const u16* gA1 = A + (size_t)(m0 + r1) * lda + s1 * 8;
        const u16* gB0 = B + (size_t)(n0 + r0) * ldb + s0 * 8;
        const u16* gB1 = B + (size_t)(n0 + r1) * ldb + s1 * 8;
        const int la0 = (w * 2 + 0) * 16 * 32;
        const int la1 = (w * 2 + 1) * 16 * 32;

        // fragment LDS indices (u16 units), constant over k
        int ia[4], ib[4];
        #pragma unroll
        for (int mi = 0; mi < 4; ++mi) {
            const int r = wr * 64 + mi * 16 + (lane & 15);
            ia[mi] = r * 32 + (((lane >> 4) ^ ((r >> 1) & 3)) << 3);
        }
        #pragma unroll
        for (int nj = 0; nj < 4; ++nj) {
            const int r = wc * 64 + nj * 16 + (lane & 15);
            ib[nj] = r * 32 + (((lane >> 4) ^ ((r >> 1) & 3)) << 3);
        }

        const int nk = kzlen >> 5;
        // prologue: stage tiles 0,1,2
        #pragma unroll
        for (int p = 0; p < 3; ++p) {
            if (p < nk) {
                const int ko = p * 32;
                gload16(gA0 + ko, &As[p][la0]);
                gload16(gA1 + ko, &As[p][la1]);
                gload16(gB0 + ko, &Bs[p][la0]);
                gload16(gB1 + ko, &Bs[p][la1]);
            }
        }
        int cur = 0;
        for (int it = 0; it < nk; ++it) {
            const int rem = nk - 1 - it;
            if (rem >= 2)      asm volatile("s_waitcnt vmcnt(8)" ::: "memory");
            else if (rem == 1) asm volatile("s_waitcnt vmcnt(4)" ::: "memory");
            else               asm volatile("s_waitcnt vmcnt(0)" ::: "memory");
            __builtin_amdgcn_s_barrier();
            short8v av[4], bv[4];
            #pragma unroll
            for (int mi = 0; mi < 4; ++mi) av[mi] = *(const short8v*)&As[cur][ia[mi]];
            #pragma unroll
            for (int nj = 0; nj < 4; ++nj) bv[nj] = *(const short8v*)&Bs[cur][ib[nj]];
            __builtin_amdgcn_s_setprio(1);
            #pragma unroll
            for (int mi = 0; mi < 4; ++mi)
                #pragma unroll
                for (int nj = 0; nj < 4; ++nj)
                    acc[mi][nj] = __builtin_amdgcn_mfma_f32_16x16x32_bf16(
                        av[mi], bv[nj], acc[mi][nj], 0, 0, 0);
            __builtin_amdgcn_s_setprio(0);
            __builtin_amdgcn_s_barrier();      // all waves done reading buf cur
            if (it + 3 < nk) {
                const int ko = (it + 3) * 32;
                gload16(gA0 + ko, &As[cur][la0]);
                gload16(gA1 + ko, &As[cur][la1]);
                gload16(gB0 + ko, &Bs[cur][la0]);
                gload16(gB1 + ko, &Bs[cur][la1]);
            }
            cur = (cur == 2) ? 0 : cur + 1;
        }
    }

    #pragma unroll
    for (int mi = 0; mi < 4; ++mi) {
        const int mbase = m0 + wr * 64 + mi * 16 + ((lane >> 4) << 2);
        #pragma unroll
        for (int nj = 0; nj < 4; ++nj) {
            const int n = n0 + wc * 64 + nj * 16 + (lane & 15);
            if (n >= Nreal) continue;
            const float bval = bias ? bias[n] : 0.f;
            #pragma unroll
            for (int r = 0; r < 4; ++r) {
                const int m = mbase + r;
                const float v = acc[mi][nj][r] + bval;
                if (n < nsplit) {
                    if (Cb) Cb[(size_t)m * ldc + n] = f2bf(v);
                    else    Cf[(size_t)m * ldc + n] = v;
                } else {
                    C2[(size_t)m * ldc2 + (n - nsplit)] = (m < act) ? v : 0.f;
                }
            }
        }
    }
}

// ---------------------------------------------------------------------------
// Attention, z-split over obj dims: grid (B, 2). Both z compute e/softmax
// (redundant); z covers awe dims [z*1024, z*1024+1024). Inactive rows exit
// early. Softmax wave-parallel on wave 0.
// ---------------------------------------------------------------------------
__global__ __launch_bounds__(256) void attn_kernel(
    const u16* __restrict__ att1b, const float* __restrict__ Hcat,
    const u16* __restrict__ objsb,
    const float* __restrict__ wfa, const float* __restrict__ bfa,
    const int* __restrict__ slen, int t,
    float* __restrict__ out_alph, u16* __restrict__ aweb)
{
    const int b = blockIdx.x, z = blockIdx.y, tid = threadIdx.x;
    const bool active = t < slen[b];
    if (!active) {
        if (z == 0 && tid < NOBJ)
            out_alph[((size_t)b * TT + t) * NOBJ + tid] = 0.f;
        return;
    }
    __shared__ float wred[4][40];
    __shared__ float es[40];
    __shared__ float alph[40];
    const int lane = tid & 63, w = tid >> 6;
    const float* hrow = Hcat + (size_t)b * 7168;
    const float4 h4 = ((const float4*)hrow)[tid];
    const float4 w4 = ((const float4*)wfa)[tid];
    const u16* a1base = att1b + (size_t)b * NOBJ * ATTD;

    float ep[NOBJ];
    #pragma unroll
    for (int n = 0; n < NOBJ; ++n) {
        ushort4 a4 = ((const ushort4*)(a1base + (size_t)n * ATTD))[tid];
        const float v0 = fmaxf(bu(a4.x) + h4.x, 0.f);
        const float v1 = fmaxf(bu(a4.y) + h4.y, 0.f);
        const float v2 = fmaxf(bu(a4.z) + h4.z, 0.f);
        const float v3 = fmaxf(bu(a4.w) + h4.w, 0.f);
        ep[n] = v0 * w4.x + v1 * w4.y + v2 * w4.z + v3 * w4.w;
    }
    #pragma unroll
    for (int n = 0; n < NOBJ; ++n) {
        float p = ep[n];
        #pragma unroll
        for (int off = 32; off > 0; off >>= 1) p += __shfl_down(p, off, 64);
        if (lane == 0) wred[w][n] = p;
    }
    __syncthreads();
    if (tid < NOBJ)
        es[tid] = wred[0][tid] + wred[1][tid] + wred[2][tid] + wred[3][tid] + bfa[0];
    __syncthreads();
    if (tid < 64) {
        float mv = (tid < NOBJ) ? es[tid] : -1e30f;
        #pragma unroll
        for (int off = 32; off > 0; off >>= 1) mv = fmaxf(mv, __shfl_xor(mv, off, 64));
        float e = (tid < NOBJ) ? expf(es[tid] - mv) : 0.f;
        float s = e;
        #pragma unroll
        for (int off = 32; off > 0; off >>= 1) s += __shfl_xor(s, off, 64);
        if (tid < NOBJ) alph[tid] = e / s;
    }
    __syncthreads();
    if (z == 0 && tid < NOBJ)
        out_alph[((size_t)b * TT + t) * NOBJ + tid] = alph[tid];

    // awe: 4 contiguous dims per thread in this z-half
    float acc[4] = {0.f, 0.f, 0.f, 0.f};
    const u16* ob = objsb + (size_t)b * NOBJ * OBJD + z * 1024 + tid * 4;
    #pragma unroll 4
    for (int n = 0; n < NOBJ; ++n) {
        const ushort4 ov = *(const ushort4*)(ob + (size_t)n * OBJD);
        const float al = alph[n];
        acc[0] = fmaf(al, bu(ov.x), acc[0]);
        acc[1] = fmaf(al, bu(ov.y), acc[1]);
        acc[2] = fmaf(al, bu(ov.z), acc[2]);
        acc[3] = fmaf(al, bu(ov.w), acc[3]);
    }
    const float4 g0 = *(const float4*)(hrow + 1024 + z * 1024 + tid * 4);
    ushort4 st;
    st.x = f2bf(acc[0] * sigf(g0.x));
    st.y = f2bf(acc[1] * sigf(g0.y));
    st.z = f2bf(acc[2] * sigf(g0.z));
    st.w = f2bf(acc[3] * sigf(g0.w));
    *(ushort4*)&aweb[(size_t)b * 2048 + z * 1024 + tid * 4] = st;
}

// ---------------------------------------------------------------------------
// LSTM elementwise: gates = sum of 4 G2 partials + Gx[t] (bf16, has biases)
// + Hcat[:,3072:]; update h,c,hb. Inactive rows exit (hb persists).
// ---------------------------------------------------------------------------
__global__ __launch_bounds__(256) void lstm_kernel(
    const float* __restrict__ G2p, const u16* __restrict__ Gxb,
    const float* __restrict__ Hcat,
    float* __restrict__ h, float* __restrict__ c, u16* __restrict__ hb,
    const int* __restrict__ slen, int t)
{
    const int idx = blockIdx.x * 256 + threadIdx.x;   // 65536 float4 lanes
    const int b = idx >> 8, d4 = idx & 255;
    if (t >= slen[b]) return;
    const float4* pw = (const float4*)(Hcat + (size_t)b * 7168 + 3072);
    const u16* gx = Gxb + ((size_t)(t * BB + b)) * 4096;

    float4 g[4];   // i,f,g,o pre-activations
    #pragma unroll
    for (int q = 0; q < 4; ++q) {
        const ushort4 xv = ((const ushort4*)(gx + q * 1024))[d4];
        float4 s;
        s.x = bu(xv.x); s.y = bu(xv.y); s.z = bu(xv.z); s.w = bu(xv.w);
        const float4 hv = pw[q * 256 + d4];
        s.x += hv.x; s.y += hv.y; s.z += hv.z; s.w += hv.w;
        #pragma unroll
        for (int p = 0; p < 4; ++p) {
            const float4 pv = ((const float4*)G2p)[(size_t)p * (BB * 1024) + b * 1024 + q * 256 + d4];
            s.x += pv.x; s.y += pv.y; s.z += pv.z; s.w += pv.w;
        }
        g[q] = s;
    }
    float4* hp = (float4*)(h + (size_t)b * 1024);
    float4* cp = (float4*)(c + (size_t)b * 1024);
    const float4 cold = cp[d4];
    float4 cn, hn;
    {
        const float si = sigf(g[0].x), sf = sigf(g[1].x), so = sigf(g[3].x);
        cn.x = sf * cold.x + si * tanhf(g[2].x); hn.x = so * tanhf(cn.x);
    }
    {
        const float si = sigf(g[0].y), sf = sigf(g[1].y), so = sigf(g[3].y);
        cn.y = sf * cold.y + si * tanhf(g[2].y); hn.y = so * tanhf(cn.y);
    }
    {
        const float si = sigf(g[0].z), sf = sigf(g[1].z), so = sigf(g[3].z);
        cn.z = sf * cold.z + si * tanhf(g[2].z); hn.z = so * tanhf(cn.z);
    }
    {
        const float si = sigf(g[0].w), sf = sigf(g[1].w), so = sigf(g[3].w);
        cn.w = sf * cold.w + si * tanhf(g[2].w); hn.w = so * tanhf(cn.w);
    }
    hp[d4] = hn;
    cp[d4] = cn;
    ushort4 s;
    s.x = f2bf(hn.x); s.y = f2bf(hn.y); s.z = f2bf(hn.z); s.w = f2bf(hn.w);
    ((ushort4*)(hb + (size_t)b * 1024))[d4] = s;
}

// ---------------------------------------------------------------------------
extern "C" void kernel_launch(void* const* d_in, const int* in_sizes, int n_in,
                              void* d_out, int out_size, void* d_ws, size_t ws_size,
                              hipStream_t stream)
{
    const float* enc  = (const float*)d_in[0];
    const float* objs = (const float*)d_in[1];
    const int*   caps = (const int*)d_in[2];
    const int*   clen = (const int*)d_in[3];
    const float* emb  = (const float*)d_in[4];
    const float* Wea  = (const float*)d_in[5];
    const float* bea  = (const float*)d_in[6];
    const float* Wda  = (const float*)d_in[7];
    const float* bda  = (const float*)d_in[8];
    const float* wfa  = (const float*)d_in[9];
    const float* bfa  = (const float*)d_in[10];
    const float* Wfb  = (const float*)d_in[11];
    const float* bfb  = (const float*)d_in[12];
    const float* Wih  = (const float*)d_in[13];
    const float* Whh  = (const float*)d_in[14];
    const float* bih  = (const float*)d_in[15];
    const float* bhh  = (const float*)d_in[16];
    const float* Wfc  = (const float*)d_in[17];
    const float* bfc  = (const float*)d_in[18];

    float* outP     = (float*)d_out;                       // (B,T,V)
    float* out_caps = outP + (size_t)BB * TT * VOCAB;      // (B,T)
    float* out_len  = out_caps + BB * TT;                  // (B,)
    float* out_alph = out_len + BB;                        // (B,T,36)
    float* out_sind = out_alph + (size_t)BB * TT * NOBJ;   // (B,)

    char* wp = (char*)d_ws;
    auto alloc = [&](size_t bytes) -> void* {
        void* r = (void*)wp;
        wp += (bytes + 255) & ~(size_t)255;
        return r;
    };
    int*   sidx  = (int*)alloc(BB * 4);
    int*   slen  = (int*)alloc(BB * 4);
    int*   cnt   = (int*)alloc(32 * 4);
    u16*   objsb = (u16*)alloc((size_t)BB * NOBJ * OBJD * 2);   // 37.75 MB
    u16*   Wbigb = (u16*)alloc((size_t)NBIGP * 1024 * 2);       // 35.4 MB
    float* bcat  = (float*)alloc(NBIGP * 4);
    u16*   Wihb  = (u16*)alloc((size_t)4096 * 3072 * 2);        // 25.2 MB
    float* bsum  = (float*)alloc(4096 * 4);
    u16*   Weab  = (u16*)alloc((size_t)1024 * OBJD * 2);        // 4.2 MB
    u16*   att1b = (u16*)alloc((size_t)BB * NOBJ * ATTD * 2);   // 18.9 MB
    u16*   Xb    = (u16*)alloc((size_t)TT * BB * DECD * 2);     // 10.5 MB
    u16*   Gxb   = (u16*)alloc((size_t)TT * BB * 4096 * 2);     // 41.9 MB
    float* Hcat  = (float*)alloc((size_t)BB * 7168 * 4);        // 7.3 MB
    u16*   aweb  = (u16*)alloc((size_t)BB * 2048 * 2);          // 1 MB
    float* G2p   = (float*)alloc((size_t)4 * BB * 4096 * 4);    // 16.8 MB
    float* h     = (float*)alloc((size_t)BB * DECD * 4);
    float* c     = (float*)alloc((size_t)BB * DECD * 4);
    u16*   hb    = (u16*)alloc((size_t)BB * DECD * 2);
    (void)ws_size; (void)in_sizes; (void)n_in; (void)out_size;

    sort_kernel<<<1, 256, 0, stream>>>(clen, sidx, slen, cnt, out_len, out_sind);
    meta_kernel<<<20, 256, 0, stream>>>(caps, sidx, out_caps);
    gather_objs<<<BB * NOBJ, 256, 0, stream>>>(objs, sidx, objsb);
    convWbig<<<NBIGP, 256, 0, stream>>>(Wda, bda, Wfb, bfb, Whh, Wfc, bfc, Wbigb, bcat);
    convWih<<<4096, 256, 0, stream>>>(Wih, bih, bhh, Wihb, bsum);
    convWea<<<1024, 256, 0, stream>>>(Wea, Weab);
    embed_kernel<<<TT * BB, 256, 0, stream>>>(enc, caps, emb, sidx, Xb);
    zero_hc<<<2048, 256, 0, stream>>>(h, c);
    hcat0_kernel<<<dim3(7, 256), 256, 0, stream>>>(bcat, Hcat);

    // att1 (bf16): M=9216, N=1024, K=2048
    gemm128<<<dim3(8, 72, 1), 256, 0, stream>>>(
        objsb, OBJD, Weab, OBJD, bea, nullptr, att1b, ATTD,
        ATTD, OBJD, 0, 0, 1 << 30, nullptr, 0, nullptr);

    // Gx = X @ Wih[:, :1024]^T + (bih+bhh) (bf16): M=5120, N=4096, K=1024
    gemm128<<<dim3(32, 40, 1), 256, 0, stream>>>(
        Xb, DECD, Wihb, 3072, bsum, nullptr, Gxb, 4096,
        4096, DECD, 0, 0, 1 << 30, nullptr, 0, nullptr);

    for (int t = 0; t < TT; ++t) {
        attn_kernel<<<dim3(BB, 2), 256, 0, stream>>>(
            att1b, Hcat, objsb, wfa, bfa, slen, t, out_alph, aweb);
        // G2 partials = awe @ Wih[:,1024:3072]^T : M=256, N=4096, K=2048 (kz=4)
        gemm128<<<dim3(64, 1, 4), 256, 0, stream>>>(
            aweb, 2048, Wihb + 1024, 3072, nullptr, G2p, nullptr, 4096,
            4096, 512, (size_t)BB * 4096, 1, 1 << 30, nullptr, 0, cnt + t);
        lstm_kernel<<<256, 256, 0, stream>>>(G2p, Gxb, Hcat, h, c, hb, slen, t);
        // fused: [Hcat(t+1) | preds(t)] = h @ Wbig^T + bcat : M=256, N=17168, K=1024
        gemm128<<<dim3(NBIGP / 64, 1, 1), 256, 0, stream>>>(
            hb, DECD, Wbigb, DECD, bcat, Hcat, nullptr, 7168,
            NBIG, DECD, 0, 1, NSPLIT, outP + (size_t)t * VOCAB, TT * VOCAB, cnt + t);
    }
}